// Round 7
// baseline (446.153 us; speedup 1.0000x reference)
//
#include <hip/hip_runtime.h>

#define CROP_H 14
#define CROP_W 14
#define IMG_H 200
#define IMG_W 200
#define IMG_C 256
#define N_IMG 8
#define N_BOXES 1000
#define PLANE (IMG_H * IMG_W)            // 40000 floats
#define IMG_TOTAL (N_IMG * IMG_C * PLANE)// 81,920,000 floats
#define HW (CROP_H * CROP_W)             // 196
#define NSLOT (2 * CROP_H)               // 28 row slots
#define BUF_STRIDE 204                   // 51 float4 per slot (max rl4=51)

// ---- Kernel A: bin boxes by n; precompute per-box coord tables + span meta.
__global__ __launch_bounds__(512) void prep_kernel(
    const float* __restrict__ boxes, const int* __restrict__ box_idx,
    int* __restrict__ order, float* __restrict__ ytab, float* __restrict__ xtab,
    int4* __restrict__ bmeta)
{
    __shared__ int counts[N_IMG];
    __shared__ int offsets[N_IMG];
    int tid  = threadIdx.x;
    int wave = tid >> 6;
    int lane = tid & 63;

    int cnt = 0;
    for (int i = lane; i < N_BOXES; i += 64) cnt += (box_idx[i] == wave) ? 1 : 0;
    for (int off = 32; off; off >>= 1) cnt += __shfl_down(cnt, off);
    if (lane == 0) counts[wave] = cnt;
    __syncthreads();
    if (tid == 0) {
        int s = 0;
        for (int i = 0; i < N_IMG; i++) { offsets[i] = s; s += counts[i]; }
    }
    __syncthreads();

    int base = offsets[wave];
    for (int i0 = 0; i0 < N_BOXES; i0 += 64) {
        int i = i0 + lane;
        bool p = (i < N_BOXES) && (box_idx[i] == wave);
        unsigned long long m = __ballot(p);
        unsigned long long below = m & ((1ull << lane) - 1ull);
        if (p) order[base + __popcll(below)] = i;
        base += __popcll(m);
    }

    // Coordinate tables (reference arithmetic order exactly; IEEE divide).
    for (int i = tid; i < N_BOXES * CROP_H; i += 512) {
        int b = i / CROP_H;
        int t = i % CROP_H;
        float y1 = boxes[b * 4 + 0];
        float x1 = boxes[b * 4 + 1];
        float y2 = boxes[b * 4 + 2];
        float x2 = boxes[b * 4 + 3];
        float h_scale = (y2 - y1) * (float)(IMG_H - 1) / (float)(CROP_H - 1);
        float w_scale = (x2 - x1) * (float)(IMG_W - 1) / (float)(CROP_W - 1);
        ytab[i] = y1 * (float)(IMG_H - 1) + (float)t * h_scale;
        xtab[i] = x1 * (float)(IMG_W - 1) + (float)t * w_scale;
    }

    // Per-box column-span meta: xmin4, rl4, 1/rl4.
    for (int b = tid; b < N_BOXES; b += 512) {
        float x1 = boxes[b * 4 + 1];
        float x2 = boxes[b * 4 + 3];
        float w_scale = (x2 - x1) * (float)(IMG_W - 1) / (float)(CROP_W - 1);
        int lxmin = IMG_W, rxmax = 0;
        for (int t = 0; t < CROP_W; t++) {
            float vx = x1 * (float)(IMG_W - 1) + (float)t * w_scale;
            if ((vx > (float)(IMG_W - 1)) || (vx < 0.0f)) vx = 0.0f;
            int lx = (int)floorf(vx);
            int rx = (int)ceilf(vx);
            lxmin = min(lxmin, lx);
            rxmax = max(rxmax, rx);
        }
        int xmin4 = lxmin & ~3;
        int rl4   = (rxmax - xmin4 + 1 + 3) >> 2;   // <= 51
        float rcp = 1.0f / (float)rl4;
        bmeta[b] = make_int4(xmin4, rl4, __float_as_int(rcp), 0);
    }
}

// ---- Kernel B: block = (channel c, box). ONE stage->barrier->compute phase.
// Stage: 28 needed rows x rl4 float4, dense coalesced. Compute: 196 bilinear
// outputs from LDS. Channel-major/box-minor grid keeps live planes ~2.6 MB.
__global__ __launch_bounds__(256) void crop_resize_kernel(
    const float* __restrict__ image,   // (8,256,200,200)
    const int*   __restrict__ box_idx, // (1000,)
    const int*   __restrict__ order,   // (1000,) n-grouped
    const float* __restrict__ ytab,    // (1000,14) raw in_y
    const float* __restrict__ xtab,    // (1000,14) raw in_x
    const int4*  __restrict__ bmeta,   // (1000,) xmin4, rl4, rcp
    float*       __restrict__ out)     // (1000,256,14,14)
{
    __shared__ int   s_slotrow[NSLOT];
    __shared__ float s_yl[CROP_H];
    __shared__ int   s_ymask[CROP_H];
    __shared__ int   s_kl[CROP_W], s_kr[CROP_W];
    __shared__ float s_xl[CROP_W];
    __shared__ int   s_xmask[CROP_W];
    __shared__ __align__(16) float buf[NSLOT][BUF_STRIDE];

    int tid = threadIdx.x;
    int pos = blockIdx.x % N_BOXES;
    int c   = blockIdx.x / N_BOXES;
    int b   = order[pos];              // uniform per block
    int n   = box_idx[b];

    int4 meta  = bmeta[b];
    int  xmin4 = meta.x;
    int  rl4   = meta.y;
    float rcp  = __int_as_float(meta.z);

    if (tid < CROP_H) {
        float vy = ytab[b * CROP_H + tid];
        int m = (vy > (float)(IMG_H - 1)) || (vy < 0.0f);
        if (m) vy = 0.0f;
        int ty = (int)floorf(vy);
        int by = (int)ceilf(vy);
        s_slotrow[2 * tid]     = ty;
        s_slotrow[2 * tid + 1] = by;
        s_yl[tid]    = vy - (float)ty;
        s_ymask[tid] = m;
    } else if (tid >= 64 && tid < 64 + CROP_W) {
        int x = tid - 64;
        float vx = xtab[b * CROP_H + x];
        int m = (vx > (float)(IMG_W - 1)) || (vx < 0.0f);
        if (m) vx = 0.0f;
        int lx = (int)floorf(vx);
        int rx = (int)ceilf(vx);
        s_kl[x]    = lx - xmin4;
        s_kr[x]    = rx - xmin4;
        s_xl[x]    = vx - (float)lx;
        s_xmask[x] = m;
    }
    __syncthreads();

    // ---- stage: 28 slots x rl4 float4, flat over threads, coalesced ----
    unsigned plane_off = ((unsigned)n * IMG_C + c) * (unsigned)PLANE;
    int total4 = NSLOT * rl4;
    for (int i = tid; i < total4; i += 256) {
        int r   = (int)(((float)i + 0.5f) * rcp);   // exact floor(i/rl4)
        int off = i - r * rl4;
        unsigned goff = plane_off + (unsigned)(s_slotrow[r] * IMG_W + xmin4 + off * 4);
        goff = min(goff, (unsigned)(IMG_TOTAL - 4));   // tail-of-image guard
        float4 v = *(const float4*)(image + goff);     // 16B-aligned
        *(float4*)&buf[r][off * 4] = v;
    }
    __syncthreads();

    // ---- compute: 196 outputs from LDS ----
    if (tid < HW) {
        int y = tid / CROP_W;
        int x = tid % CROP_W;
        int kl = s_kl[x], kr = s_kr[x];
        float xl = s_xl[x];
        float yl = s_yl[y];
        float tl = buf[2 * y][kl];
        float tr = buf[2 * y][kr];
        float bl = buf[2 * y + 1][kl];
        float br = buf[2 * y + 1][kr];
        float top = tl + xl * (tr - tl);
        float bot = bl + xl * (br - bl);
        float v   = top + yl * (bot - top);
        if (s_ymask[y] | s_xmask[x]) v = 0.0f;
        size_t oidx = ((size_t)b * IMG_C + c) * (size_t)HW + tid;
        __builtin_nontemporal_store(v, &out[oidx]);
    }
}

extern "C" void kernel_launch(void* const* d_in, const int* in_sizes, int n_in,
                              void* d_out, int out_size, void* d_ws, size_t ws_size,
                              hipStream_t stream) {
    const float* image   = (const float*)d_in[0];
    const float* boxes   = (const float*)d_in[1];
    const int*   box_idx = (const int*)d_in[2];
    float* out  = (float*)d_out;

    // ws: order(4000B)@0 | ytab(56000B)@4096 | xtab(56000B)@60096 | bmeta@116096
    int*   order = (int*)d_ws;
    float* ytab  = (float*)((char*)d_ws + 4096);
    float* xtab  = ytab + N_BOXES * CROP_H;
    int4*  bmeta = (int4*)((char*)d_ws + 116096);

    prep_kernel<<<1, 512, 0, stream>>>(boxes, box_idx, order, ytab, xtab, bmeta);

    int grid = N_BOXES * IMG_C;   // 256,000 blocks, channel-major
    crop_resize_kernel<<<grid, 256, 0, stream>>>(image, box_idx, order,
                                                 ytab, xtab, bmeta, out);
}

// Round 8
// 329.164 us; speedup vs baseline: 1.3554x; 1.3554x over previous
//
#include <hip/hip_runtime.h>

#define CROP_H 14
#define CROP_W 14
#define IMG_H 200
#define IMG_W 200
#define IMG_C 256
#define N_IMG 8
#define N_BOXES 1000
#define PLANE (IMG_H * IMG_W)
#define HW (CROP_H * CROP_W)             // 196

// ---- Kernel A: bin boxes by n; precompute per-(box,t) coord tables.
__global__ __launch_bounds__(512) void prep_kernel(
    const float* __restrict__ boxes, const int* __restrict__ box_idx,
    int* __restrict__ order, float* __restrict__ ytab, float* __restrict__ xtab)
{
    __shared__ int counts[N_IMG];
    __shared__ int offsets[N_IMG];
    int tid  = threadIdx.x;
    int wave = tid >> 6;
    int lane = tid & 63;

    int cnt = 0;
    for (int i = lane; i < N_BOXES; i += 64) cnt += (box_idx[i] == wave) ? 1 : 0;
    for (int off = 32; off; off >>= 1) cnt += __shfl_down(cnt, off);
    if (lane == 0) counts[wave] = cnt;
    __syncthreads();
    if (tid == 0) {
        int s = 0;
        for (int i = 0; i < N_IMG; i++) { offsets[i] = s; s += counts[i]; }
    }
    __syncthreads();

    int base = offsets[wave];
    for (int i0 = 0; i0 < N_BOXES; i0 += 64) {
        int i = i0 + lane;
        bool p = (i < N_BOXES) && (box_idx[i] == wave);
        unsigned long long m = __ballot(p);
        unsigned long long below = m & ((1ull << lane) - 1ull);
        if (p) order[base + __popcll(below)] = i;
        base += __popcll(m);
    }

    // Raw coordinates (reference arithmetic order exactly; IEEE divide).
    for (int i = tid; i < N_BOXES * CROP_H; i += 512) {
        int b = i / CROP_H;
        int t = i % CROP_H;
        float y1 = boxes[b * 4 + 0];
        float x1 = boxes[b * 4 + 1];
        float y2 = boxes[b * 4 + 2];
        float x2 = boxes[b * 4 + 3];
        float h_scale = (y2 - y1) * (float)(IMG_H - 1) / (float)(CROP_H - 1);
        float w_scale = (x2 - x1) * (float)(IMG_W - 1) / (float)(CROP_W - 1);
        ytab[i] = y1 * (float)(IMG_H - 1) + (float)t * h_scale;
        xtab[i] = x1 * (float)(IMG_W - 1) + (float)t * w_scale;
    }
}

// ---- Kernel B: direct bilinear (R4's proven tap path), block = (channel,
// box). XCD-pinned channels: blockIdx%8 selects the XCD (round-robin
// dispatch), and we put c%8 there -> each (n,c) plane is fetched by exactly
// ONE XCD's L2, eliminating cross-XCD line duplication. Within an XCD,
// boxes sweep n-grouped (box-minor) so the live set is ~2.6 MB < 4 MB L2.
__global__ __launch_bounds__(256) void crop_resize_kernel(
    const float* __restrict__ image,   // (8,256,200,200)
    const int*   __restrict__ box_idx, // (1000,)
    const int*   __restrict__ order,   // (1000,) n-grouped
    const float* __restrict__ ytab,    // (1000,14) raw in_y
    const float* __restrict__ xtab,    // (1000,14) raw in_x
    float*       __restrict__ out)     // (1000,256,14,14)
{
    int tid = threadIdx.x;
    if (tid >= HW) return;              // 196 active threads

    int xcd = blockIdx.x & 7;
    int j   = blockIdx.x >> 3;          // [0, 32000)
    int pos = j % N_BOXES;              // box position (n-grouped), minor
    int chi = j / N_BOXES;              // [0, 32) channel-high, major
    int c   = chi * 8 + xcd;            // channel pinned to XCD

    int b = order[pos];                 // uniform per block
    int n = box_idx[b];

    int y = tid / CROP_W;
    int x = tid % CROP_W;

    float vy = ytab[b * CROP_H + y];
    float vx = xtab[b * CROP_H + x];

    size_t oidx = ((size_t)b * IMG_C + c) * (size_t)HW + tid;

    bool bad = (vy > (float)(IMG_H - 1)) || (vy < 0.0f) ||
               (vx > (float)(IMG_W - 1)) || (vx < 0.0f);
    if (bad) { __builtin_nontemporal_store(0.0f, &out[oidx]); return; }

    int ty = (int)floorf(vy);
    int by = (int)ceilf(vy);
    int lx = (int)floorf(vx);
    int rx = (int)ceilf(vx);
    float yl = vy - (float)ty;
    float xl = vx - (float)lx;

    const float* __restrict__ plane =
        image + ((size_t)n * IMG_C + c) * (size_t)PLANE;

    float tl = plane[ty * IMG_W + lx];
    float tr = plane[ty * IMG_W + rx];
    float bl = plane[by * IMG_W + lx];
    float br = plane[by * IMG_W + rx];

    float top = tl + xl * (tr - tl);
    float bot = bl + xl * (br - bl);
    float v   = top + yl * (bot - top);
    __builtin_nontemporal_store(v, &out[oidx]);
}

extern "C" void kernel_launch(void* const* d_in, const int* in_sizes, int n_in,
                              void* d_out, int out_size, void* d_ws, size_t ws_size,
                              hipStream_t stream) {
    const float* image   = (const float*)d_in[0];
    const float* boxes   = (const float*)d_in[1];
    const int*   box_idx = (const int*)d_in[2];
    float* out  = (float*)d_out;

    // ws: order (1000 int) @0 | ytab (1000*14 f32) @4096 | xtab after
    int*   order = (int*)d_ws;
    float* ytab  = (float*)((char*)d_ws + 4096);
    float* xtab  = ytab + N_BOXES * CROP_H;

    prep_kernel<<<1, 512, 0, stream>>>(boxes, box_idx, order, ytab, xtab);

    int grid = N_BOXES * IMG_C;   // 256,000 blocks
    crop_resize_kernel<<<grid, 256, 0, stream>>>(image, box_idx, order,
                                                 ytab, xtab, out);
}